// Round 12
// baseline (602.487 us; speedup 1.0000x reference)
//
#include <hip/hip_runtime.h>
#include <math.h>

#define NRW 131072
#define W   128
#define K   1024
#define C   4
#define BN  128
#define NT  1024

typedef _Float16 f16;
typedef _Float16 f16x8 __attribute__((ext_vector_type(8)));
typedef float    f32x4 __attribute__((ext_vector_type(4)));

__device__ __forceinline__ float fmulr(float a, float b){ return __fmul_rn(a,b); }
__device__ __forceinline__ float faddr(float a, float b){ return __fadd_rn(a,b); }
__device__ __forceinline__ float fsubr(float a, float b){ return __fsub_rn(a,b); }
__device__ __forceinline__ unsigned umin32(unsigned a, unsigned b){ return a < b ? a : b; }
__device__ __forceinline__ unsigned umax32(unsigned a, unsigned b){ return a > b ? a : b; }

// XLA:CPU reduce bits: acc = fl(acc + fl(v*v)), ascending, init 0
__device__ float seq_sumsq_glb(const float* __restrict__ p){
    float a = 0.f;
    for (int w = 0; w < W; ++w){ const float v = p[w]; a = faddr(a, fmulr(v, v)); }
    return a;
}

__global__ __launch_bounds__(256) void c2_kernel(const float* __restrict__ CB,
                                                 float* __restrict__ c2g){
    const int kg = blockIdx.x * 256 + threadIdx.x;
    if (kg < C * K) c2g[kg] = seq_sumsq_glb(CB + (size_t)kg * W);
}

// f16 hi/lo split, fragment-major B layout for mfma_f32_16x16x32_f16 (verified R9/R10):
// off = (((s*64 + (k>>4))*4 + q)*64 + ((w8&3)*16 + (k&15)))*8, q = w>>5, w8 = w>>3
__global__ __launch_bounds__(256) void split_kernel(const float* __restrict__ CB,
                                                    f16* __restrict__ Bh, f16* __restrict__ Bl){
    const int g  = blockIdx.x * 256 + threadIdx.x;     // 65536 total
    const int s  = g >> 14, k = (g >> 4) & 1023, w8 = g & 15;
    const float* src = CB + ((size_t)(s * K + k)) * W + w8 * 8;
    const size_t off = ((((size_t)(s * 64 + (k >> 4)) * 4 + (w8 >> 2)) * 64)
                        + ((w8 & 3) * 16 + (k & 15))) * 8;
    f16x8 hv, lv;
    #pragma unroll
    for (int j = 0; j < 8; ++j){
        const float x = src[j];
        const f16 h = (f16)x;
        hv[j] = h;
        lv[j] = (f16)(x - (float)h);
    }
    *(f16x8*)(Bh + off) = hv;
    *(f16x8*)(Bl + off) = lv;
}

#define DPP_TOP2(p1, p2, RCTL)                                                          \
    {                                                                                   \
        const unsigned q1 = (unsigned)__builtin_amdgcn_update_dpp((int)(p1), (int)(p1), \
                                                                  (RCTL), 0xF, 0xF, false); \
        const unsigned q2 = (unsigned)__builtin_amdgcn_update_dpp((int)(p2), (int)(p2), \
                                                                  (RCTL), 0xF, 0xF, false); \
        const unsigned t = umax32(p1, q1);                                              \
        p1 = umin32(p1, q1);                                                            \
        p2 = umin32(t, umin32(p2, q2));                                                 \
    }

#define PACK_INS(ACCV, C2V, KPK, S1, S2)                                                \
    {                                                                                   \
        const float sv = fmaf(-2.f, (ACCV), (C2V));                                     \
        const int   bb = __float_as_int(sv);                                            \
        const unsigned uu = ((unsigned)(bb ^ ((bb >> 31) | (int)0x80000000))            \
                             & 0xFFFFFC00u) | (KPK);                                    \
        const unsigned tmn = umin32((S1), uu);                                          \
        (S2) = umin32((S2), umax32((S1), uu));                                          \
        (S1) = tmn;                                                                     \
    }

__global__ __launch_bounds__(NT, 4) void rq12_kernel(
    const float* __restrict__ X, const float* __restrict__ CB,
    const float* __restrict__ c2g, const f16* __restrict__ BhG,
    const f16* __restrict__ BlG, float* __restrict__ out)
{
    __shared__ float Rt[BN][W + 1];                 // stride 129
    __shared__ __attribute__((aligned(16))) f16 AH[8 * 4 * 64 * 8];   // 32 KB A hi (frag-major)
    __shared__ __attribute__((aligned(16))) f16 AL[8 * 4 * 64 * 8];   // 32 KB A lo
    __shared__ unsigned long long mslot[BN * 17];   // [row][unit=wv], row stride 17
    __shared__ int   cand[BN][2];
    __shared__ float dve[BN][2];
    __shared__ int   widx[BN];

    const int tid = threadIdx.x;
    const int wv  = tid >> 6;      // 0..15: 64-k slice owner
    const int ln  = tid & 63;
    const int col = ln & 15;
    const int n0  = blockIdx.x * BN;

    // ---- initial residual = X ----
    for (int e = tid; e < BN * 32; e += NT){
        const int row = e >> 5, q = e & 31;
        const float4 v = *(const float4*)(X + (size_t)(n0 + row) * W + q * 4);
        float* rp = &Rt[row][q * 4];
        rp[0] = v.x; rp[1] = v.y; rp[2] = v.z; rp[3] = v.w;
    }

    for (int st = 0; st < C; ++st){
        const float*  cb  = CB + (size_t)st * K * W;
        const float4* cb4 = (const float4*)cb;

        __syncthreads();   // Rt stable

        // ---- extract A fragments -> f16 hi/lo LDS; init mslot ----
        for (int s = tid; s < 2048; s += NT){
            const int frag = s >> 6, lns = s & 63;
            const int row = ((frag >> 2) << 4) + (lns & 15);
            const int w0  = ((frag & 3) << 5) + ((lns >> 4) << 3);
            const float* rp = &Rt[row][w0];
            f16x8 h, l;
            #pragma unroll
            for (int j = 0; j < 8; ++j){
                const float x = rp[j];
                const f16 hh = (f16)x;
                h[j] = hh;
                l[j] = (f16)(x - (float)hh);
            }
            *(f16x8*)&AH[s * 8] = h;
            *(f16x8*)&AL[s * 8] = l;
        }
        for (int s = tid; s < BN * 17; s += NT) mslot[s] = ~0ull;
        __syncthreads();   // AH/AL + mslot ready

        // ---- MFMA scan: wave owns kb in [wv*4, wv*4+4); stream 1 kb of B at a time ----
        // per-stage fragment stride = 64 kb * 4 q * 64 lanes * 8 f16 = 131072 (R11 bug: was 65536)
        const f16* BhS = BhG + (size_t)st * 131072;
        const f16* BlS = BlG + (size_t)st * 131072;

        #pragma unroll 1
        for (int ch = 0; ch < 2; ++ch){
            unsigned s1a[4][4], s2a[4][4];
            #pragma unroll
            for (int a = 0; a < 4; ++a)
                #pragma unroll
                for (int b = 0; b < 4; ++b){ s1a[a][b] = 0xFFFFFFFFu; s2a[a][b] = 0xFFFFFFFFu; }

            #pragma unroll 1
            for (int kbi = 0; kbi < 4; ++kbi){
                const int kb = wv * 4 + kbi;
                f16x8 bh[4], bl[4];
                #pragma unroll
                for (int q = 0; q < 4; ++q){
                    const size_t fo = ((size_t)(kb * 4 + q) * 64 + ln) * 8;
                    bh[q] = *(const f16x8*)(BhS + fo);
                    bl[q] = *(const f16x8*)(BlS + fo);
                }
                const unsigned kpk = (unsigned)((kb << 4) + col);
                const float    c2v = c2g[st * K + (int)kpk];

                #pragma unroll 1
                for (int rbl = 0; rbl < 4; ++rbl){
                    const int rb = ch * 4 + rbl;
                    f32x4 acc = {0.f, 0.f, 0.f, 0.f};
                    {   // hi passes first (ah live), then lo pass (al reuses ah's regs)
                        f16x8 ah0 = *(const f16x8*)&AH[(((rb * 4 + 0) * 64) + ln) * 8];
                        f16x8 ah1 = *(const f16x8*)&AH[(((rb * 4 + 1) * 64) + ln) * 8];
                        f16x8 ah2 = *(const f16x8*)&AH[(((rb * 4 + 2) * 64) + ln) * 8];
                        f16x8 ah3 = *(const f16x8*)&AH[(((rb * 4 + 3) * 64) + ln) * 8];
                        acc = __builtin_amdgcn_mfma_f32_16x16x32_f16(ah0, bh[0], acc, 0, 0, 0);
                        acc = __builtin_amdgcn_mfma_f32_16x16x32_f16(ah1, bh[1], acc, 0, 0, 0);
                        acc = __builtin_amdgcn_mfma_f32_16x16x32_f16(ah2, bh[2], acc, 0, 0, 0);
                        acc = __builtin_amdgcn_mfma_f32_16x16x32_f16(ah3, bh[3], acc, 0, 0, 0);
                        acc = __builtin_amdgcn_mfma_f32_16x16x32_f16(ah0, bl[0], acc, 0, 0, 0);
                        acc = __builtin_amdgcn_mfma_f32_16x16x32_f16(ah1, bl[1], acc, 0, 0, 0);
                        acc = __builtin_amdgcn_mfma_f32_16x16x32_f16(ah2, bl[2], acc, 0, 0, 0);
                        acc = __builtin_amdgcn_mfma_f32_16x16x32_f16(ah3, bl[3], acc, 0, 0, 0);
                    }
                    {
                        f16x8 al0 = *(const f16x8*)&AL[(((rb * 4 + 0) * 64) + ln) * 8];
                        f16x8 al1 = *(const f16x8*)&AL[(((rb * 4 + 1) * 64) + ln) * 8];
                        f16x8 al2 = *(const f16x8*)&AL[(((rb * 4 + 2) * 64) + ln) * 8];
                        f16x8 al3 = *(const f16x8*)&AL[(((rb * 4 + 3) * 64) + ln) * 8];
                        acc = __builtin_amdgcn_mfma_f32_16x16x32_f16(al0, bh[0], acc, 0, 0, 0);
                        acc = __builtin_amdgcn_mfma_f32_16x16x32_f16(al1, bh[1], acc, 0, 0, 0);
                        acc = __builtin_amdgcn_mfma_f32_16x16x32_f16(al2, bh[2], acc, 0, 0, 0);
                        acc = __builtin_amdgcn_mfma_f32_16x16x32_f16(al3, bh[3], acc, 0, 0, 0);
                    }
                    if (rbl == 0){ PACK_INS(acc[0], c2v, kpk, s1a[0][0], s2a[0][0]);
                                   PACK_INS(acc[1], c2v, kpk, s1a[0][1], s2a[0][1]);
                                   PACK_INS(acc[2], c2v, kpk, s1a[0][2], s2a[0][2]);
                                   PACK_INS(acc[3], c2v, kpk, s1a[0][3], s2a[0][3]); }
                    if (rbl == 1){ PACK_INS(acc[0], c2v, kpk, s1a[1][0], s2a[1][0]);
                                   PACK_INS(acc[1], c2v, kpk, s1a[1][1], s2a[1][1]);
                                   PACK_INS(acc[2], c2v, kpk, s1a[1][2], s2a[1][2]);
                                   PACK_INS(acc[3], c2v, kpk, s1a[1][3], s2a[1][3]); }
                    if (rbl == 2){ PACK_INS(acc[0], c2v, kpk, s1a[2][0], s2a[2][0]);
                                   PACK_INS(acc[1], c2v, kpk, s1a[2][1], s2a[2][1]);
                                   PACK_INS(acc[2], c2v, kpk, s1a[2][2], s2a[2][2]);
                                   PACK_INS(acc[3], c2v, kpk, s1a[2][3], s2a[2][3]); }
                    if (rbl == 3){ PACK_INS(acc[0], c2v, kpk, s1a[3][0], s2a[3][0]);
                                   PACK_INS(acc[1], c2v, kpk, s1a[3][1], s2a[3][1]);
                                   PACK_INS(acc[2], c2v, kpk, s1a[3][2], s2a[3][2]);
                                   PACK_INS(acc[3], c2v, kpk, s1a[3][3], s2a[3][3]); }
                }
            }

            // flush: DPP top-2 across the 16 col-lanes, write unit slot
            #pragma unroll
            for (int rbl = 0; rbl < 4; ++rbl){
                #pragma unroll
                for (int rg = 0; rg < 4; ++rg){
                    unsigned p1 = s1a[rbl][rg], p2 = s2a[rbl][rg];
                    DPP_TOP2(p1, p2, 0x121)   // row_ror:1
                    DPP_TOP2(p1, p2, 0x122)   // row_ror:2
                    DPP_TOP2(p1, p2, 0x124)   // row_ror:4
                    DPP_TOP2(p1, p2, 0x128)   // row_ror:8
                    if (col == 0){
                        const int row = (ch * 4 + rbl) * 16 + ((ln >> 4) << 2) + rg;
                        mslot[row * 17 + wv] =
                            ((unsigned long long)p2 << 32) | (unsigned long long)p1;
                    }
                }
            }
        }
        __syncthreads();   // all unit top-2 written

        // ---- final merge: top-2 over 16 units (32 packed values) per row ----
        if (tid < BN){
            unsigned b1 = 0xFFFFFFFFu, b2 = 0xFFFFFFFFu;
            for (int i = 0; i < 16; ++i){
                const int ii = (i + tid) & 15;
                const unsigned long long v = mslot[tid * 17 + ii];
                const unsigned lo = (unsigned)v, hi = (unsigned)(v >> 32);
                if (lo < b1){ b2 = b1; b1 = lo; } else if (lo < b2) b2 = lo;
                if (hi < b1){ b2 = b1; b1 = hi; } else if (hi < b2) b2 = hi;
            }
            cand[tid][0] = (int)(b1 & 1023u);
            cand[tid][1] = (int)(b2 & 1023u);
        }
        __syncthreads();

        // ---- exact XLA-bits re-eval of both candidates ----
        if (tid < 2 * BN){
            const int row = tid >> 1, cd = tid & 1;
            const int k = cand[row][cd];
            const float* cw = cb + (size_t)k * W;
            float r2 = 0.f, dot = 0.f;
            for (int w = 0; w < W; ++w){
                const float rv = Rt[row][w];
                r2  = faddr(r2, fmulr(rv, rv));
                dot = __fmaf_rn(rv, cw[w], dot);
            }
            dve[row][cd] = faddr(fsubr(r2, faddr(dot, dot)), c2g[st * K + k]);
        }
        __syncthreads();

        // ---- decide (lexicographic: XLA first-min) + outputs ----
        if (tid < BN){
            const float a0 = dve[tid][0], a1 = dve[tid][1];
            const int   i0 = cand[tid][0], i1 = cand[tid][1];
            int wi; float wd;
            if (a1 < a0 || (a1 == a0 && i1 < i0)){ wi = i1; wd = a1; } else { wi = i0; wd = a0; }
            widx[tid] = wi;
            out[(size_t)st * NRW + (n0 + tid)] = (float)wi;
            out[(size_t)C * NRW + (size_t)(n0 + tid) * C + st] = __fsqrt_rn(fmaxf(wd, 0.f));
        }
        __syncthreads();

        // ---- residual -= cb[idx], elementwise f32 (bit-exact) ----
        if (st < C - 1){
            for (int e = tid; e < BN * 32; e += NT){
                const int row = e >> 5, q = e & 31;
                const float4 v = cb4[(size_t)widx[row] * 32 + q];
                float* rp = &Rt[row][q * 4];
                rp[0] = fsubr(rp[0], v.x);
                rp[1] = fsubr(rp[1], v.y);
                rp[2] = fsubr(rp[2], v.z);
                rp[3] = fsubr(rp[3], v.w);
            }
        }
    }
}

extern "C" void kernel_launch(void* const* d_in, const int* in_sizes, int n_in,
                              void* d_out, int out_size, void* d_ws, size_t ws_size,
                              hipStream_t stream) {
    const float* X  = (const float*)d_in[0];
    const float* CB = (const float*)d_in[1];
    float* out = (float*)d_out;

    float* c2g = (float*)d_ws;                              // 16 KB
    f16*   Bh  = (f16*)((char*)d_ws + 16384);               // 1 MB
    f16*   Bl  = (f16*)((char*)d_ws + 16384 + 1048576);     // 1 MB

    c2_kernel<<<dim3((C * K + 255) / 256), 256, 0, stream>>>(CB, c2g);
    split_kernel<<<dim3(C * K * 16 / 256), 256, 0, stream>>>(CB, Bh, Bl);
    rq12_kernel<<<dim3(NRW / BN), NT, 0, stream>>>(X, CB, c2g, Bh, Bl, out);
}